// Round 10
// baseline (120.164 us; speedup 1.0000x reference)
//
#include <hip/hip_runtime.h>
#include <math.h>

#define NEG_SLOPE 0.2f
#define EPS_F 1e-16f
#define CIN 128
#define HC 64
#define BSH 6              // bucket shift: 64 nodes per bucket
#define BNODES 64
#define NBKT 2048          // bucket count (tgt >> 6), max node 131071 (N < 2^17)
#define PBLK 256           // partition blocks
#define CSR_CAP 2048       // LDS csr capacity per bucket (avg ~1025, max ~1200)

typedef _Float16 f16;
typedef _Float16 f16x8 __attribute__((ext_vector_type(8)));
typedef float f32x4  __attribute__((ext_vector_type(4)));

// ---- fused: projection (fp16 MFMA) + P1 bucket histogram (LDS atomics) ----
__global__ __launch_bounds__(256) void proj_p1(
    const float* __restrict__ x, const float* __restrict__ W,
    const float* __restrict__ att, f16* __restrict__ h,
    float* __restrict__ asrc, float* __restrict__ atgt, int N,
    const int* __restrict__ tgt, int* __restrict__ cnt, int E, int EPB,
    int projB)
{
    __shared__ f16 sWt[HC][CIN + 8];
    __shared__ int lh[NBKT];

    if ((int)blockIdx.x >= projB) {
        int pb = blockIdx.x - projB;
        for (int i = threadIdx.x; i < NBKT; i += 256) lh[i] = 0;
        __syncthreads();
        int e0 = pb * EPB, e1 = min(E, e0 + EPB);
        for (int e = e0 + threadIdx.x; e < e1; e += 256)
            atomicAdd(&lh[((unsigned)tgt[e]) >> BSH], 1);
        __syncthreads();
        for (int b = threadIdx.x; b < NBKT; b += 256)
            cnt[b * PBLK + pb] = lh[b];
        return;
    }

    int rowBase = blockIdx.x * 64;
    for (int i = threadIdx.x; i < CIN * HC; i += 256) {
        int k = i >> 6, c = i & 63;
        sWt[c][k] = (f16)W[i];
    }
    __syncthreads();

    int lane = threadIdx.x & 63;
    int wv   = threadIdx.x >> 6;
    int mrow = lane & 15, g = lane >> 4;
    int r16  = rowBase + wv * 16;

    f16x8 bfrag[4][4];
#pragma unroll
    for (int nt = 0; nt < 4; ++nt)
#pragma unroll
        for (int kc = 0; kc < 4; ++kc)
            bfrag[nt][kc] = *reinterpret_cast<const f16x8*>(&sWt[nt * 16 + mrow][kc * 32 + g * 8]);

    int arow = r16 + mrow;
    const float* xr = x + (size_t)(arow < N ? arow : N - 1) * CIN;
    float4 xa[4][2];
#pragma unroll
    for (int kc = 0; kc < 4; ++kc) {
        xa[kc][0] = *reinterpret_cast<const float4*>(xr + kc * 32 + g * 8);
        xa[kc][1] = *reinterpret_cast<const float4*>(xr + kc * 32 + g * 8 + 4);
    }

    f32x4 acc[4] = {};
#pragma unroll
    for (int kc = 0; kc < 4; ++kc) {
        f16x8 a;
        a[0] = (f16)xa[kc][0].x; a[1] = (f16)xa[kc][0].y;
        a[2] = (f16)xa[kc][0].z; a[3] = (f16)xa[kc][0].w;
        a[4] = (f16)xa[kc][1].x; a[5] = (f16)xa[kc][1].y;
        a[6] = (f16)xa[kc][1].z; a[7] = (f16)xa[kc][1].w;
#pragma unroll
        for (int nt = 0; nt < 4; ++nt)
            acc[nt] = __builtin_amdgcn_mfma_f32_16x16x32_f16(a, bfrag[nt][kc], acc[nt], 0, 0, 0);
    }

#pragma unroll
    for (int nt = 0; nt < 4; ++nt) {
        int c = nt * 16 + mrow;
        float as_w = att[(c >> 3) * 16 + (c & 7)];
        float at_w = att[(c >> 3) * 16 + 8 + (c & 7)];
#pragma unroll
        for (int q = 0; q < 4; ++q) {
            int n = r16 + g * 4 + q;
            float v = acc[nt][q];
            if (n < N) h[(size_t)n * HC + c] = (f16)v;
            float vs = v * as_w, vt = v * at_w;
            vs += __shfl_xor(vs, 1); vs += __shfl_xor(vs, 2); vs += __shfl_xor(vs, 4);
            vt += __shfl_xor(vt, 1); vt += __shfl_xor(vt, 2); vt += __shfl_xor(vt, 4);
            if ((lane & 7) == 0 && n < N) {
                asrc[n * 8 + (c >> 3)] = vs;
                atgt[n * 8 + (c >> 3)] = vt;
            }
        }
    }
}

// ---- scan level 1 ---------------------------------------------------------
__global__ __launch_bounds__(1024) void scan_block(const int* __restrict__ in,
                                                   int* __restrict__ out,
                                                   int* __restrict__ bsum, int M)
{
    __shared__ int s[1024];
    int i = blockIdx.x * 1024 + threadIdx.x;
    int v = (i < M) ? in[i] : 0;
    s[threadIdx.x] = v;
    __syncthreads();
    for (int d = 1; d < 1024; d <<= 1) {
        int t = (threadIdx.x >= (unsigned)d) ? s[threadIdx.x - d] : 0;
        __syncthreads();
        s[threadIdx.x] += t;
        __syncthreads();
    }
    if (i < M) out[i + 1] = s[threadIdx.x];
    if (threadIdx.x == 1023) bsum[blockIdx.x] = s[1023];
}

// ---- scan level 2 (fused) -------------------------------------------------
__global__ __launch_bounds__(1024) void scan_add2(int* __restrict__ out,
                                                  const int* __restrict__ bsum,
                                                  int M, int nb)
{
    __shared__ int sPre;
    int t = threadIdx.x;
    if (t < 64) {
        int sum = 0;
        for (int j = t; j < nb; j += 64)
            if (j < (int)blockIdx.x) sum += bsum[j];
        sum += __shfl_xor(sum, 1);  sum += __shfl_xor(sum, 2);
        sum += __shfl_xor(sum, 4);  sum += __shfl_xor(sum, 8);
        sum += __shfl_xor(sum, 16); sum += __shfl_xor(sum, 32);
        if (t == 0) sPre = sum;
    }
    __syncthreads();
    int pre = sPre;
    int i = blockIdx.x * 1024 + t;
    if (i < M) out[i + 1] += pre;
    if (i == 0) out[0] = 0;
}

// ---- P3: partition edges into bucket regions; packed (src | local_tgt<<17)
__global__ __launch_bounds__(256) void p3_partition(
    const int* __restrict__ src, const int* __restrict__ tgt,
    const int* __restrict__ matScan, int* __restrict__ pairs, int E, int EPB)
{
    __shared__ int lh[NBKT];
    for (int i = threadIdx.x; i < NBKT; i += 256) lh[i] = 0;
    __syncthreads();
    int e0 = blockIdx.x * EPB, e1 = min(E, e0 + EPB);
    for (int e = e0 + threadIdx.x; e < e1; e += 256) {
        int t = tgt[e];
        int bkt = ((unsigned)t) >> BSH;
        int r = atomicAdd(&lh[bkt], 1);
        int pos = matScan[bkt * PBLK + blockIdx.x] + r;
        pairs[pos] = src[e] | ((t & (BNODES - 1)) << 17);
    }
}

// ---- fused P4 + gather: bucket sort in LDS, degree-ordered softmax+agg ----
__global__ __launch_bounds__(256) void p4_gather(
    const int* __restrict__ pairs, const int* __restrict__ matScan,
    const f16* __restrict__ h, const float* __restrict__ asrc,
    const float* __restrict__ atgt, const float* __restrict__ bias,
    int* __restrict__ csr_g, float* __restrict__ out, int N)
{
    __shared__ int hist[BNODES], scanS[BNODES], fill[BNODES], order[BNODES];
    __shared__ int h2[64], s2[64];
    __shared__ int csrL[CSR_CAP];

    int b = blockIdx.x;
    int base = matScan[b * PBLK];
    int size = matScan[(b + 1) * PBLK] - base;
    int bN0 = b << BSH;
    int tid = threadIdx.x;
    bool lds_ok = (size <= CSR_CAP);

    if (tid < BNODES) { hist[tid] = 0; fill[tid] = 0; }
    else if (tid < BNODES + 64) h2[tid - BNODES] = 0;
    __syncthreads();

    for (int k = tid; k < size; k += 256)
        atomicAdd(&hist[((unsigned)pairs[base + k]) >> 17], 1);
    __syncthreads();

    int myrank = 0, mybin = 0;
    if (tid < BNODES) {
        scanS[tid] = hist[tid];
        mybin = min(hist[tid], 63);
        myrank = atomicAdd(&h2[mybin], 1);
    }
    __syncthreads();
    for (int d = 1; d < BNODES; d <<= 1) {
        int t = (tid >= (unsigned)d && tid < BNODES) ? scanS[tid - d] : 0;
        __syncthreads();
        if (tid < BNODES) scanS[tid] += t;
        __syncthreads();
    }

    // serial 64-bin exclusive scan (thread 0) runs concurrently with scatter
    if (tid == 0) {
        int run = 0;
        for (int i = 0; i < 64; ++i) { int t = h2[i]; s2[i] = run; run += t; }
    }
    if (lds_ok) {
        for (int k = tid; k < size; k += 256) {
            int p = pairs[base + k];
            int j = ((unsigned)p) >> 17;
            int r = atomicAdd(&fill[j], 1);
            csrL[scanS[j] - hist[j] + r] = p & 0x1FFFF;
        }
    } else {
        for (int k = tid; k < size; k += 256) {
            int p = pairs[base + k];
            int j = ((unsigned)p) >> 17;
            int r = atomicAdd(&fill[j], 1);
            csr_g[base + scanS[j] - hist[j] + r] = p & 0x1FFFF;
        }
    }
    __syncthreads();
    if (tid < BNODES) order[s2[mybin] + myrank] = tid;
    __syncthreads();

    // ---- gather: 2 passes x 32 degree-adjacent nodes, 8 lanes/node ----
    unsigned lh8 = tid & 7;
    unsigned c0  = lh8 * 8u;

#define GBODY(CSRLD)                                                          \
    for (; k + 4 <= k1; k += 4) {                                             \
        unsigned S0 = (unsigned)CSRLD(k),     S1 = (unsigned)CSRLD(k + 1);    \
        unsigned S2 = (unsigned)CSRLD(k + 2), S3 = (unsigned)CSRLD(k + 3);    \
        float A0 = asrc[S0 * 8u + lh8] + at, A1 = asrc[S1 * 8u + lh8] + at;   \
        float A2 = asrc[S2 * 8u + lh8] + at, A3 = asrc[S3 * 8u + lh8] + at;   \
        f16x8 H0 = *reinterpret_cast<const f16x8*>(&h[S0 * 64u + c0]);        \
        f16x8 H1 = *reinterpret_cast<const f16x8*>(&h[S1 * 64u + c0]);        \
        f16x8 H2 = *reinterpret_cast<const f16x8*>(&h[S2 * 64u + c0]);        \
        f16x8 H3 = *reinterpret_cast<const f16x8*>(&h[S3 * 64u + c0]);        \
        A0 = fmaxf(A0, NEG_SLOPE * A0); A1 = fmaxf(A1, NEG_SLOPE * A1);       \
        A2 = fmaxf(A2, NEG_SLOPE * A2); A3 = fmaxf(A3, NEG_SLOPE * A3);       \
        float w0 = __expf(A0), w1 = __expf(A1);                               \
        float w2 = __expf(A2), w3 = __expf(A3);                               \
        ssum += (w0 + w1) + (w2 + w3);                                        \
        _Pragma("unroll")                                                     \
        for (int i = 0; i < 8; ++i)                                           \
            acc[i] += (w0 * (float)H0[i] + w1 * (float)H1[i])                 \
                    + (w2 * (float)H2[i] + w3 * (float)H3[i]);                \
    }                                                                         \
    for (; k < k1; ++k) {                                                     \
        unsigned S0 = (unsigned)CSRLD(k);                                     \
        float A0 = asrc[S0 * 8u + lh8] + at;                                  \
        f16x8 H0 = *reinterpret_cast<const f16x8*>(&h[S0 * 64u + c0]);        \
        A0 = fmaxf(A0, NEG_SLOPE * A0);                                       \
        float w0 = __expf(A0);                                                \
        ssum += w0;                                                           \
        _Pragma("unroll")                                                     \
        for (int i = 0; i < 8; ++i) acc[i] += w0 * (float)H0[i];              \
    }

    for (int g = 0; g < BNODES; g += 32) {
        int ln   = order[g + (tid >> 3)];
        int node = bN0 + ln;
        if (node >= N) continue;
        int k1 = scanS[ln];
        int k  = k1 - hist[ln];
        float at = atgt[(unsigned)node * 8u + lh8];
        float ssum = 0.f;
        float acc[8] = {0.f, 0.f, 0.f, 0.f, 0.f, 0.f, 0.f, 0.f};

        if (lds_ok) {
#define CLD(i) csrL[i]
            GBODY(CLD)
#undef CLD
        } else {
#define CGD(i) csr_g[base + (i)]
            GBODY(CGD)
#undef CGD
        }

        float inv = 1.f / fmaxf(ssum, EPS_F);
        float4 b0 = *reinterpret_cast<const float4*>(&bias[c0]);
        float4 b1 = *reinterpret_cast<const float4*>(&bias[c0 + 4]);
        float4 o0, o1;
        o0.x = acc[0] * inv + b0.x; o0.y = acc[1] * inv + b0.y;
        o0.z = acc[2] * inv + b0.z; o0.w = acc[3] * inv + b0.w;
        o1.x = acc[4] * inv + b1.x; o1.y = acc[5] * inv + b1.y;
        o1.z = acc[6] * inv + b1.z; o1.w = acc[7] * inv + b1.w;
        float* op = &out[(size_t)node * HC + c0];
        *reinterpret_cast<float4*>(op)     = o0;
        *reinterpret_cast<float4*>(op + 4) = o1;
    }
}

extern "C" void kernel_launch(void* const* d_in, const int* in_sizes, int n_in,
                              void* d_out, int out_size, void* d_ws, size_t ws_size,
                              hipStream_t stream)
{
    const float* x    = (const float*)d_in[0];
    const int*   ei   = (const int*)d_in[1];
    const float* W    = (const float*)d_in[2];
    const float* att  = (const float*)d_in[3];
    const float* bias = (const float*)d_in[4];
    float* out = (float*)d_out;

    int N = in_sizes[0] / CIN;
    int E = in_sizes[1] / 2;
    const int* src = ei;
    const int* tgt = ei + E;

    const int M = NBKT * PBLK;                    // 524288 count-matrix entries

    // workspace carve-up (~36 MB)
    f16*   h       = (f16*)d_ws;                  // N*64 fp16       (12.8 MB)
    float* asrc    = (float*)(h + (size_t)N * HC);// N*8             (3.2 MB)
    float* atgt    = asrc + (size_t)N * 8;        // N*8             (3.2 MB)
    int*   cnt     = (int*)(atgt + (size_t)N * 8);// M               (2 MB)
    int*   matScan = cnt + M;                     // M+1             (2 MB)
    int*   bsum    = matScan + M + 2;             // 512
    int*   pairs   = bsum + 1024;                 // E               (6.4 MB)
    int*   csr_g   = pairs + E;                   // E fallback      (6.4 MB)

    int EPB = (E + PBLK - 1) / PBLK;
    int projB = (N + 63) / 64;

    proj_p1<<<projB + PBLK, 256, 0, stream>>>(x, W, att, h, asrc, atgt, N,
                                              tgt, cnt, E, EPB, projB);

    scan_block<<<M / 1024, 1024, 0, stream>>>(cnt, matScan, bsum, M);
    scan_add2<<<M / 1024, 1024, 0, stream>>>(matScan, bsum, M, M / 1024);

    p3_partition<<<PBLK, 256, 0, stream>>>(src, tgt, matScan, pairs, E, EPB);

    p4_gather<<<(N + BNODES - 1) / BNODES, 256, 0, stream>>>(
        pairs, matScan, h, asrc, atgt, bias, csr_g, out, N);
}

// Round 11
// 114.669 us; speedup vs baseline: 1.0479x; 1.0479x over previous
//
#include <hip/hip_runtime.h>
#include <math.h>

#define NEG_SLOPE 0.2f
#define EPS_F 1e-16f
#define CIN 128
#define HC 64
#define BSH 7              // bucket shift: 128 nodes per bucket
#define BNODES 128
#define NBKT 1024          // bucket count (tgt >> 7), max node 131071 (N < 2^17)
#define PBLK 256           // partition blocks
#define CSR_CAP 4096       // LDS csr capacity per bucket (avg ~2050, max ~2300)

typedef _Float16 f16;
typedef _Float16 f16x8 __attribute__((ext_vector_type(8)));
typedef float f32x4  __attribute__((ext_vector_type(4)));

// ---- fused: projection (fp16 MFMA) + P1 bucket histogram (LDS atomics) ----
__global__ __launch_bounds__(256) void proj_p1(
    const float* __restrict__ x, const float* __restrict__ W,
    const float* __restrict__ att, f16* __restrict__ h,
    float* __restrict__ asrc, float* __restrict__ atgt, int N,
    const int* __restrict__ tgt, int* __restrict__ cnt, int E, int EPB,
    int projB)
{
    __shared__ f16 sWt[HC][CIN + 8];
    __shared__ int lh[NBKT];

    if ((int)blockIdx.x >= projB) {
        int pb = blockIdx.x - projB;
        for (int i = threadIdx.x; i < NBKT; i += 256) lh[i] = 0;
        __syncthreads();
        int e0 = pb * EPB, e1 = min(E, e0 + EPB);
        for (int e = e0 + threadIdx.x; e < e1; e += 256)
            atomicAdd(&lh[((unsigned)tgt[e]) >> BSH], 1);
        __syncthreads();
        for (int b = threadIdx.x; b < NBKT; b += 256)
            cnt[b * PBLK + pb] = lh[b];
        return;
    }

    int rowBase = blockIdx.x * 64;
    for (int i = threadIdx.x; i < CIN * HC; i += 256) {
        int k = i >> 6, c = i & 63;
        sWt[c][k] = (f16)W[i];
    }
    __syncthreads();

    int lane = threadIdx.x & 63;
    int wv   = threadIdx.x >> 6;
    int mrow = lane & 15, g = lane >> 4;
    int r16  = rowBase + wv * 16;

    f16x8 bfrag[4][4];
#pragma unroll
    for (int nt = 0; nt < 4; ++nt)
#pragma unroll
        for (int kc = 0; kc < 4; ++kc)
            bfrag[nt][kc] = *reinterpret_cast<const f16x8*>(&sWt[nt * 16 + mrow][kc * 32 + g * 8]);

    int arow = r16 + mrow;
    const float* xr = x + (size_t)(arow < N ? arow : N - 1) * CIN;
    float4 xa[4][2];
#pragma unroll
    for (int kc = 0; kc < 4; ++kc) {
        xa[kc][0] = *reinterpret_cast<const float4*>(xr + kc * 32 + g * 8);
        xa[kc][1] = *reinterpret_cast<const float4*>(xr + kc * 32 + g * 8 + 4);
    }

    f32x4 acc[4] = {};
#pragma unroll
    for (int kc = 0; kc < 4; ++kc) {
        f16x8 a;
        a[0] = (f16)xa[kc][0].x; a[1] = (f16)xa[kc][0].y;
        a[2] = (f16)xa[kc][0].z; a[3] = (f16)xa[kc][0].w;
        a[4] = (f16)xa[kc][1].x; a[5] = (f16)xa[kc][1].y;
        a[6] = (f16)xa[kc][1].z; a[7] = (f16)xa[kc][1].w;
#pragma unroll
        for (int nt = 0; nt < 4; ++nt)
            acc[nt] = __builtin_amdgcn_mfma_f32_16x16x32_f16(a, bfrag[nt][kc], acc[nt], 0, 0, 0);
    }

#pragma unroll
    for (int nt = 0; nt < 4; ++nt) {
        int c = nt * 16 + mrow;
        float as_w = att[(c >> 3) * 16 + (c & 7)];
        float at_w = att[(c >> 3) * 16 + 8 + (c & 7)];
#pragma unroll
        for (int q = 0; q < 4; ++q) {
            int n = r16 + g * 4 + q;
            float v = acc[nt][q];
            if (n < N) h[(size_t)n * HC + c] = (f16)v;
            float vs = v * as_w, vt = v * at_w;
            vs += __shfl_xor(vs, 1); vs += __shfl_xor(vs, 2); vs += __shfl_xor(vs, 4);
            vt += __shfl_xor(vt, 1); vt += __shfl_xor(vt, 2); vt += __shfl_xor(vt, 4);
            if ((lane & 7) == 0 && n < N) {
                asrc[n * 8 + (c >> 3)] = vs;
                atgt[n * 8 + (c >> 3)] = vt;
            }
        }
    }
}

// ---- scan level 1 ---------------------------------------------------------
__global__ __launch_bounds__(1024) void scan_block(const int* __restrict__ in,
                                                   int* __restrict__ out,
                                                   int* __restrict__ bsum, int M)
{
    __shared__ int s[1024];
    int i = blockIdx.x * 1024 + threadIdx.x;
    int v = (i < M) ? in[i] : 0;
    s[threadIdx.x] = v;
    __syncthreads();
    for (int d = 1; d < 1024; d <<= 1) {
        int t = (threadIdx.x >= (unsigned)d) ? s[threadIdx.x - d] : 0;
        __syncthreads();
        s[threadIdx.x] += t;
        __syncthreads();
    }
    if (i < M) out[i + 1] = s[threadIdx.x];
    if (threadIdx.x == 1023) bsum[blockIdx.x] = s[1023];
}

// ---- scan level 2 (fused) -------------------------------------------------
__global__ __launch_bounds__(1024) void scan_add2(int* __restrict__ out,
                                                  const int* __restrict__ bsum,
                                                  int M, int nb)
{
    __shared__ int sPre;
    int t = threadIdx.x;
    if (t < 64) {
        int sum = 0;
        for (int j = t; j < nb; j += 64)
            if (j < (int)blockIdx.x) sum += bsum[j];
        sum += __shfl_xor(sum, 1);  sum += __shfl_xor(sum, 2);
        sum += __shfl_xor(sum, 4);  sum += __shfl_xor(sum, 8);
        sum += __shfl_xor(sum, 16); sum += __shfl_xor(sum, 32);
        if (t == 0) sPre = sum;
    }
    __syncthreads();
    int pre = sPre;
    int i = blockIdx.x * 1024 + t;
    if (i < M) out[i + 1] += pre;
    if (i == 0) out[0] = 0;
}

// ---- P3: partition edges into bucket regions; packed (src | local_tgt<<17)
__global__ __launch_bounds__(256) void p3_partition(
    const int* __restrict__ src, const int* __restrict__ tgt,
    const int* __restrict__ matScan, int* __restrict__ pairs, int E, int EPB)
{
    __shared__ int lh[NBKT];
    for (int i = threadIdx.x; i < NBKT; i += 256) lh[i] = 0;
    __syncthreads();
    int e0 = blockIdx.x * EPB, e1 = min(E, e0 + EPB);
    for (int e = e0 + threadIdx.x; e < e1; e += 256) {
        int t = tgt[e];
        int bkt = ((unsigned)t) >> BSH;
        int r = atomicAdd(&lh[bkt], 1);
        int pos = matScan[bkt * PBLK + blockIdx.x] + r;
        pairs[pos] = src[e] | ((t & (BNODES - 1)) << 17);
    }
}

// ---- fused P4 + gather: 512 threads (8 waves) for occupancy ---------------
__global__ __launch_bounds__(512) void p4_gather(
    const int* __restrict__ pairs, const int* __restrict__ matScan,
    const f16* __restrict__ h, const float* __restrict__ asrc,
    const float* __restrict__ atgt, const float* __restrict__ bias,
    int* __restrict__ csr_g, float* __restrict__ out, int N)
{
    __shared__ int hist[BNODES], scanS[BNODES], fill[BNODES], order[BNODES];
    __shared__ int h2[64], s2[64];
    __shared__ int csrL[CSR_CAP];

    int b = blockIdx.x;
    int base = matScan[b * PBLK];
    int size = matScan[(b + 1) * PBLK] - base;
    int bN0 = b << BSH;
    int tid = threadIdx.x;
    bool lds_ok = (size <= CSR_CAP);

    if (tid < BNODES) { hist[tid] = 0; fill[tid] = 0; }
    else if (tid < BNODES + 64) h2[tid - BNODES] = 0;
    __syncthreads();

    for (int k = tid; k < size; k += 512)
        atomicAdd(&hist[((unsigned)pairs[base + k]) >> 17], 1);
    __syncthreads();

    int myrank = 0, mybin = 0;
    if (tid < BNODES) {
        scanS[tid] = hist[tid];
        mybin = min(hist[tid], 63);
        myrank = atomicAdd(&h2[mybin], 1);
    }
    __syncthreads();
    for (int d = 1; d < BNODES; d <<= 1) {
        int t = (tid >= (unsigned)d && tid < BNODES) ? scanS[tid - d] : 0;
        __syncthreads();
        if (tid < BNODES) scanS[tid] += t;
        __syncthreads();
    }

    // serial 64-bin exclusive scan (thread 0) runs concurrently with scatter
    if (tid == 0) {
        int run = 0;
        for (int i = 0; i < 64; ++i) { int t = h2[i]; s2[i] = run; run += t; }
    }
    if (lds_ok) {
        for (int k = tid; k < size; k += 512) {
            int p = pairs[base + k];
            int j = ((unsigned)p) >> 17;
            int r = atomicAdd(&fill[j], 1);
            csrL[scanS[j] - hist[j] + r] = p & 0x1FFFF;
        }
    } else {
        for (int k = tid; k < size; k += 512) {
            int p = pairs[base + k];
            int j = ((unsigned)p) >> 17;
            int r = atomicAdd(&fill[j], 1);
            csr_g[base + scanS[j] - hist[j] + r] = p & 0x1FFFF;
        }
    }
    __syncthreads();
    if (tid < BNODES) order[s2[mybin] + myrank] = tid;
    __syncthreads();

    // ---- gather: 2 passes x 64 degree-adjacent nodes, 8 lanes/node ----
    unsigned lh8 = tid & 7;
    unsigned c0  = lh8 * 8u;

#define GBODY(CSRLD)                                                          \
    for (; k + 4 <= k1; k += 4) {                                             \
        unsigned S0 = (unsigned)CSRLD(k),     S1 = (unsigned)CSRLD(k + 1);    \
        unsigned S2 = (unsigned)CSRLD(k + 2), S3 = (unsigned)CSRLD(k + 3);    \
        float A0 = asrc[S0 * 8u + lh8] + at, A1 = asrc[S1 * 8u + lh8] + at;   \
        float A2 = asrc[S2 * 8u + lh8] + at, A3 = asrc[S3 * 8u + lh8] + at;   \
        f16x8 H0 = *reinterpret_cast<const f16x8*>(&h[S0 * 64u + c0]);        \
        f16x8 H1 = *reinterpret_cast<const f16x8*>(&h[S1 * 64u + c0]);        \
        f16x8 H2 = *reinterpret_cast<const f16x8*>(&h[S2 * 64u + c0]);        \
        f16x8 H3 = *reinterpret_cast<const f16x8*>(&h[S3 * 64u + c0]);        \
        A0 = fmaxf(A0, NEG_SLOPE * A0); A1 = fmaxf(A1, NEG_SLOPE * A1);       \
        A2 = fmaxf(A2, NEG_SLOPE * A2); A3 = fmaxf(A3, NEG_SLOPE * A3);       \
        float w0 = __expf(A0), w1 = __expf(A1);                               \
        float w2 = __expf(A2), w3 = __expf(A3);                               \
        ssum += (w0 + w1) + (w2 + w3);                                        \
        _Pragma("unroll")                                                     \
        for (int i = 0; i < 8; ++i)                                           \
            acc[i] += (w0 * (float)H0[i] + w1 * (float)H1[i])                 \
                    + (w2 * (float)H2[i] + w3 * (float)H3[i]);                \
    }                                                                         \
    for (; k < k1; ++k) {                                                     \
        unsigned S0 = (unsigned)CSRLD(k);                                     \
        float A0 = asrc[S0 * 8u + lh8] + at;                                  \
        f16x8 H0 = *reinterpret_cast<const f16x8*>(&h[S0 * 64u + c0]);        \
        A0 = fmaxf(A0, NEG_SLOPE * A0);                                       \
        float w0 = __expf(A0);                                                \
        ssum += w0;                                                           \
        _Pragma("unroll")                                                     \
        for (int i = 0; i < 8; ++i) acc[i] += w0 * (float)H0[i];              \
    }

    for (int g = 0; g < BNODES; g += 64) {
        int ln   = order[g + (tid >> 3)];
        int node = bN0 + ln;
        if (node >= N) continue;
        int k1 = scanS[ln];
        int k  = k1 - hist[ln];
        float at = atgt[(unsigned)node * 8u + lh8];
        float ssum = 0.f;
        float acc[8] = {0.f, 0.f, 0.f, 0.f, 0.f, 0.f, 0.f, 0.f};

        if (lds_ok) {
#define CLD(i) csrL[i]
            GBODY(CLD)
#undef CLD
        } else {
#define CGD(i) csr_g[base + (i)]
            GBODY(CGD)
#undef CGD
        }

        float inv = 1.f / fmaxf(ssum, EPS_F);
        float4 b0 = *reinterpret_cast<const float4*>(&bias[c0]);
        float4 b1 = *reinterpret_cast<const float4*>(&bias[c0 + 4]);
        float4 o0, o1;
        o0.x = acc[0] * inv + b0.x; o0.y = acc[1] * inv + b0.y;
        o0.z = acc[2] * inv + b0.z; o0.w = acc[3] * inv + b0.w;
        o1.x = acc[4] * inv + b1.x; o1.y = acc[5] * inv + b1.y;
        o1.z = acc[6] * inv + b1.z; o1.w = acc[7] * inv + b1.w;
        float* op = &out[(size_t)node * HC + c0];
        *reinterpret_cast<float4*>(op)     = o0;
        *reinterpret_cast<float4*>(op + 4) = o1;
    }
}

extern "C" void kernel_launch(void* const* d_in, const int* in_sizes, int n_in,
                              void* d_out, int out_size, void* d_ws, size_t ws_size,
                              hipStream_t stream)
{
    const float* x    = (const float*)d_in[0];
    const int*   ei   = (const int*)d_in[1];
    const float* W    = (const float*)d_in[2];
    const float* att  = (const float*)d_in[3];
    const float* bias = (const float*)d_in[4];
    float* out = (float*)d_out;

    int N = in_sizes[0] / CIN;
    int E = in_sizes[1] / 2;
    const int* src = ei;
    const int* tgt = ei + E;

    const int M = NBKT * PBLK;                    // 262144 count-matrix entries

    // workspace carve-up (~34 MB)
    f16*   h       = (f16*)d_ws;                  // N*64 fp16       (12.8 MB)
    float* asrc    = (float*)(h + (size_t)N * HC);// N*8             (3.2 MB)
    float* atgt    = asrc + (size_t)N * 8;        // N*8             (3.2 MB)
    int*   cnt     = (int*)(atgt + (size_t)N * 8);// M               (1 MB)
    int*   matScan = cnt + M;                     // M+1             (1 MB)
    int*   bsum    = matScan + M + 2;             // 256
    int*   pairs   = bsum + 1024;                 // E               (6.4 MB)
    int*   csr_g   = pairs + E;                   // E fallback      (6.4 MB)

    int EPB = (E + PBLK - 1) / PBLK;
    int projB = (N + 63) / 64;

    proj_p1<<<projB + PBLK, 256, 0, stream>>>(x, W, att, h, asrc, atgt, N,
                                              tgt, cnt, E, EPB, projB);

    scan_block<<<M / 1024, 1024, 0, stream>>>(cnt, matScan, bsum, M);
    scan_add2<<<M / 1024, 1024, 0, stream>>>(matScan, bsum, M, M / 1024);

    p3_partition<<<PBLK, 256, 0, stream>>>(src, tgt, matScan, pairs, E, EPB);

    p4_gather<<<(N + BNODES - 1) / BNODES, 512, 0, stream>>>(
        pairs, matScan, h, asrc, atgt, bias, csr_g, out, N);
}